// Round 10
// baseline (395.947 us; speedup 1.0000x reference)
//
#include <hip/hip_runtime.h>
#include <cstdint>
#include <cstddef>

// SummaryAdapter fused kernel for MI355X (gfx950), v10: counted-vmcnt DMA
// pipeline. P1 stages h via global_load_lds into a 4-buffer ring with raw
// s_barrier + vmcnt(6) (2 chunks of DMA permanently in flight, never drained
// by barriers). Wq/Wo/h consumed via register prefetch one chunk ahead
// (pair-unrolled, static names). P5 uses raw barrier + lgkmcnt(0) only.
// L=8 B=2 S=4096 D=2048 N=128 Ds=1024 Da=64.
//
// LDS map (20608 B), lifetime-aliased:
//   stage ring: 4 x 1024B/wave = [0,16384)   (P1; chunk c -> buf c&3)
//   scb f32 stride 128 @0       (P2 write, P3 read; stage dead)
//   Pb  u16 stride 136 @8448    (P3 write, P4 read)
//   qsc f32 stride 66  @16384   (end-P1 write, P2 read)
//   aob f32 stride 66  @16384   (P4 write, P5 read; qsc dead)
//   resb u16[16][264] dbuf @0 / @4224  (P5; scb dead)
//
// Workspace layout (bytes):          off      size
//   KF  frag bf16                      0    262144
//   VF  frag bf16                 262144    262144
//   WqF frag bf16                 524288   2097152
//   WoF frag bf16                2621440   2097152
// Requires ws_size >= 4718592.

typedef __attribute__((ext_vector_type(8))) short short8;   // 8 x bf16
typedef __attribute__((ext_vector_type(4))) float f32x4;
typedef __attribute__((ext_vector_type(4))) unsigned short u16x4;

#define MFMA16(a, b, c) __builtin_amdgcn_mfma_f32_16x16x32_bf16((a), (b), (c), 0, 0, 0)

__device__ __forceinline__ unsigned short f2bf(float f) {
  unsigned int x = __builtin_bit_cast(unsigned int, f);
  x += 0x7fffu + ((x >> 16) & 1u);        // RNE
  return (unsigned short)(x >> 16);
}
__device__ __forceinline__ float bf2f(unsigned short u) {
  return __builtin_bit_cast(float, (unsigned int)u << 16);
}
__device__ __forceinline__ short8 cvt8v(f32x4 a, f32x4 b) {
  short8 r;
  r[0] = (short)f2bf(a[0]); r[1] = (short)f2bf(a[1]);
  r[2] = (short)f2bf(a[2]); r[3] = (short)f2bf(a[3]);
  r[4] = (short)f2bf(b[0]); r[5] = (short)f2bf(b[1]);
  r[6] = (short)f2bf(b[2]); r[7] = (short)f2bf(b[3]);
  return r;
}
__device__ __forceinline__ short8 ld_cvt8(const float* p) {
  f32x4 v0 = *(const f32x4*)p, v1 = *(const f32x4*)(p + 4);
  return cvt8v(v0, v1);
}
__device__ __forceinline__ u16x4 pack4(f32x4 v) {
  u16x4 r;
  r[0] = f2bf(v[0]); r[1] = f2bf(v[1]); r[2] = f2bf(v[2]); r[3] = f2bf(v[3]);
  return r;
}
// async 16B/lane global->LDS DMA; lds base wave-uniform, global per-lane
__device__ __forceinline__ void gload_lds16(const void* g, void* l) {
  typedef __attribute__((address_space(1))) const unsigned int gu32;
  typedef __attribute__((address_space(3))) unsigned int lu32;
  __builtin_amdgcn_global_load_lds((gu32*)(const unsigned int*)g,
                                   (lu32*)(unsigned int*)l, 16, 0, 0);
}

// ---------------- pre 1: K = bank@Wk^T, V = bank@Wv^T via MFMA -------------
__global__ __launch_bounds__(64)
void pre_kv_kernel(const float* __restrict__ bank,
                   const float* __restrict__ Wk,
                   const float* __restrict__ Wv,
                   unsigned short* __restrict__ KF, unsigned short* __restrict__ VF) {
  int bid = blockIdx.x;
  int at = bid & 3, nt = (bid >> 2) & 7, kv = (bid >> 5) & 1;
  int b = (bid >> 6) & 1, l = bid >> 7;
  int lane = threadIdx.x & 63;
  int lo = lane & 15, hi = lane >> 4;
  const float* W  = (kv ? Wv : Wk) + (size_t)l * 65536;
  const float* bk = bank + (size_t)b * 131072;
  int lbq = l * 2 + b;
  f32x4 acc = (f32x4){0.f, 0.f, 0.f, 0.f};
  for (int ks = 0; ks < 32; ++ks) {
    short8 A = ld_cvt8(bk + (nt * 16 + lo) * 1024 + ks * 32 + hi * 8);
    short8 B = ld_cvt8(W + (at * 16 + lo) * 1024 + ks * 32 + hi * 8);
    acc = MFMA16(A, B, acc);
  }
  for (int r = 0; r < 4; ++r) {
    int n = nt * 16 + hi * 4 + r;
    int a = at * 16 + lo;
    unsigned short v = f2bf(acc[r]);
    if (kv == 0) {
      int idx = ((lbq * 8 + (n >> 4)) * 2 + (a >> 5)) * 512 +
                (((a >> 3) & 3) * 16 + (n & 15)) * 8 + (a & 7);
      KF[idx] = v;
    } else {
      int idx = ((lbq * 4 + (a >> 4)) * 4 + (n >> 5)) * 512 +
                (((n >> 3) & 3) * 16 + (a & 15)) * 8 + (n & 7);
      VF[idx] = v;
    }
  }
}

// ---------------- pre 2: Wq/Wo -> bf16 fragment layout ---------------------
__global__ void pre_frag_kernel(const float* __restrict__ Wq, const float* __restrict__ Wo,
                                unsigned short* __restrict__ WqF, unsigned short* __restrict__ WoF) {
  int idx = blockIdx.x * 256 + threadIdx.x;        // 262144 threads
  if (idx < 131072) {
    int t = idx;
    int lane = t & 63, ks = (t >> 6) & 63, at = (t >> 12) & 3, l = t >> 14;
    int a = at * 16 + (lane & 15), d = ks * 32 + (lane >> 4) * 8;
    *(short8*)(WqF + (size_t)t * 8) = ld_cvt8(Wq + ((size_t)(l * 64 + a)) * 2048 + d);
  } else {
    int t = idx - 131072;
    int lane = t & 63, ks = (t >> 6) & 1, dt = (t >> 7) & 127, l = t >> 14;
    int d = dt * 16 + (lane & 15), a = ks * 32 + (lane >> 4) * 8;
    *(short8*)(WoF + (size_t)t * 8) = ld_cvt8(Wo + ((size_t)(l * 2048 + d)) * 64 + a);
  }
}

// ---------------- main fused kernel ----------------------------------------
__global__ __launch_bounds__(256, 6)
void adapter_main(const float* __restrict__ hidden,
                  const unsigned short* __restrict__ KF, const unsigned short* __restrict__ VF,
                  const unsigned short* __restrict__ WqF, const unsigned short* __restrict__ WoF,
                  const float* __restrict__ gates, float* __restrict__ out) {
  __shared__ __align__(16) char smem[20608];
  float* scb = (float*)smem;                           // stride 128 f32
  unsigned short* Pb = (unsigned short*)(smem + 8448); // stride 136 u16
  float* qsc = (float*)(smem + 16384);                 // stride 66 f32
  float* aob = (float*)(smem + 16384);                 // stride 66 f32

  // XCD-bijective swizzle (4096 % 8 == 0): XCD x gets 512 tiles = layer x.
  int bid0 = blockIdx.x;
  int bid = (bid0 & 7) * 512 + (bid0 >> 3);
  int st = bid & 255, b = (bid >> 8) & 1, l = bid >> 9;
  int tid = threadIdx.x, wave = tid >> 6, lane = tid & 63;
  int lo = lane & 15, hi = lane >> 4;
  int l32 = lane & 31, lh = lane >> 5;
  size_t hbase = ((size_t)(l * 2 + b) * 4096 + st * 16) * 2048;
  const char* hby = (const char*)(hidden + hbase);
  float gate = 1.0f / (1.0f + __expf(-gates[l]));
  int lb = l * 2 + b;
  int at = wave;
  char* stg = smem;

  // ---- Phase 1: Q = h @ Wq^T; 32 chunks of 16 rows x 256B, 4-buf DMA ring.
  // DMA: wave w's one instr covers rows 4w..4w+3 (lane>>4), slots lane&15,
  // global source pre-swizzled slot*16 ^ ((row&7)<<5) => conflict-free reads.
  f32x4 qacc = (f32x4){0.f, 0.f, 0.f, 0.f};
  {
    const unsigned short* wqb = WqF + ((size_t)(l * 4 + at) * 64) * 512 + lane * 8;
    int rowg = wave * 4 + hi;                      // this lane's staged row... (hi = lane>>4 only for lo-split; need lane>>4 of 0..3)
    rowg = wave * 4 + (lane >> 4) - hi + hi;       // keep as computed below
    int r4 = lane >> 4;                            // 0..3
    rowg = wave * 4 + r4;
    size_t gsw = (size_t)(((lane & 15) * 16) ^ ((rowg & 7) << 5));
    const char* gsrc = hby + (size_t)rowg * 8192 + gsw;
    char* ldst = stg + wave * 1024;
    int swr = (lo & 7) << 5;

#define DMA1(c) gload_lds16(gsrc + (size_t)(c) * 256, ldst + ((c) & 3) * 4096)
#define BLD(c, dst)                                                          \
    do {                                                                     \
      dst##0 = *(const short8*)(wqb + (size_t)(2 * (c)) * 512);              \
      dst##1 = *(const short8*)(wqb + (size_t)(2 * (c) + 1) * 512);          \
    } while (0)
#define P1BODY(c, Br)                                                        \
    do {                                                                     \
      const char* rb = stg + ((c) & 3) * 4096 + lo * 256;                    \
      int y0 = (hi * 32) ^ swr, y1 = (128 + hi * 32) ^ swr;                  \
      short8 A0 = cvt8v(*(const f32x4*)(rb + y0), *(const f32x4*)(rb + y0 + 16)); \
      short8 A1 = cvt8v(*(const f32x4*)(rb + y1), *(const f32x4*)(rb + y1 + 16)); \
      qacc = MFMA16(A0, Br##0, qacc);                                        \
      qacc = MFMA16(A1, Br##1, qacc);                                        \
    } while (0)

    short8 Be0, Be1, Bo0, Bo1;
    DMA1(0); DMA1(1); BLD(0, Be);
    #pragma unroll 1
    for (int p = 0; p < 16; ++p) {
      int c = 2 * p;
      // even chunk c: uses Be; prefetch DMA(c+2) + B(c+1)
      if (p < 15) { DMA1(c + 2); }
      BLD(c + 1, Bo);
      if (p < 15) { asm volatile("s_waitcnt vmcnt(6)" ::: "memory"); }
      else        { asm volatile("s_waitcnt vmcnt(5)" ::: "memory"); }
      __builtin_amdgcn_s_barrier();
      P1BODY(c, Be);
      // odd chunk c+1: uses Bo; prefetch DMA(c+3) + B(c+2)
      if (p < 15) {
        DMA1(c + 3);
        BLD(c + 2, Be);
        asm volatile("s_waitcnt vmcnt(6)" ::: "memory");
      } else {
        asm volatile("s_waitcnt vmcnt(2)" ::: "memory");
      }
      __builtin_amdgcn_s_barrier();
      P1BODY(c + 1, Bo);
    }
#undef DMA1
#undef BLD
#undef P1BODY
  }

  // write Q (scaled) -> qsc @16384 (disjoint from stage ring)
  #pragma unroll
  for (int r = 0; r < 4; ++r)                      // fold 1/sqrt(64)
    qsc[(hi * 4 + r) * 66 + at * 16 + lo] = qacc[r] * 0.125f;
  __syncthreads();

  // ---- Phase 2: afrag from qsc; scores = Q @ K^T -> scb (disjoint) ----
  {
    short8 afrag[2];
    #pragma unroll
    for (int ks = 0; ks < 2; ++ks) {
      const float* qp = qsc + lo * 66 + ks * 32 + hi * 8;
      afrag[ks] = cvt8v(*(const f32x4*)qp, *(const f32x4*)(qp + 4));
    }
    #pragma unroll
    for (int i = 0; i < 2; ++i) {
      int nt = wave * 2 + i;
      f32x4 acc = (f32x4){0.f, 0.f, 0.f, 0.f};
      const unsigned short* kf = KF + ((size_t)(lb * 8 + nt) * 2) * 512 + lane * 8;
      acc = MFMA16(afrag[0], *(const short8*)(kf), acc);
      acc = MFMA16(afrag[1], *(const short8*)(kf + 512), acc);
      #pragma unroll
      for (int r = 0; r < 4; ++r)
        scb[(hi * 4 + r) * 128 + nt * 16 + lo] = acc[r];
    }
  }
  __syncthreads();

  // ---- Phase 3: softmax over N=128 (16 lanes per row) -> Pb bf16 ----
  {
    int row = wave * 4 + hi;
    const float* sp = scb + row * 128 + lo * 8;
    f32x4 v0 = *(const f32x4*)sp, v1 = *(const f32x4*)(sp + 4);
    float m = fmaxf(fmaxf(fmaxf(v0[0], v0[1]), fmaxf(v0[2], v0[3])),
                    fmaxf(fmaxf(v1[0], v1[1]), fmaxf(v1[2], v1[3])));
    m = fmaxf(m, __shfl_xor(m, 1)); m = fmaxf(m, __shfl_xor(m, 2));
    m = fmaxf(m, __shfl_xor(m, 4)); m = fmaxf(m, __shfl_xor(m, 8));
    f32x4 e0, e1; float s = 0.f;
    #pragma unroll
    for (int j = 0; j < 4; ++j) { e0[j] = __expf(v0[j] - m); s += e0[j]; }
    #pragma unroll
    for (int j = 0; j < 4; ++j) { e1[j] = __expf(v1[j] - m); s += e1[j]; }
    s += __shfl_xor(s, 1); s += __shfl_xor(s, 2);
    s += __shfl_xor(s, 4); s += __shfl_xor(s, 8);
    float inv = 1.0f / s;
    #pragma unroll
    for (int j = 0; j < 4; ++j) { e0[j] *= inv; e1[j] *= inv; }
    *(short8*)((char*)Pb + row * 272 + lo * 16) = cvt8v(e0, e1);
  }
  __syncthreads();

  // ---- Phase 4: attn_out = P @ V -> aob (qsc dead) ----
  {
    short8 pfrag[4];
    #pragma unroll
    for (int ks = 0; ks < 4; ++ks)
      pfrag[ks] = *(const short8*)((const char*)Pb + lo * 272 + ks * 64 + hi * 16);
    const unsigned short* vf = VF + ((size_t)(lb * 4 + at) * 4) * 512 + lane * 8;
    f32x4 a = (f32x4){0.f, 0.f, 0.f, 0.f};
    #pragma unroll
    for (int ks = 0; ks < 4; ++ks)
      a = MFMA16(pfrag[ks], *(const short8*)(vf + (size_t)ks * 512), a);
    #pragma unroll
    for (int r = 0; r < 4; ++r)
      aob[(hi * 4 + r) * 66 + at * 16 + lo] = a[r];
  }
  __syncthreads();

  // ---- Phase 5: 16 d-chunks, raw barrier (lgkm only) + reg prefetch ----
  {
    short8 bfrag[2];
    #pragma unroll
    for (int ks = 0; ks < 2; ++ks) {
      const float* ap2 = aob + lo * 66 + ks * 32 + hi * 8;
      bfrag[ks] = cvt8v(*(const f32x4*)ap2, *(const f32x4*)(ap2 + 4));
    }
    const unsigned short* wobase = WoF + (size_t)l * 131072 + lane * 8;
    char* ob = (char*)(out + hbase);
    int hr0 = wave * 2 + lh, hr1 = 8 + wave * 2 + lh;

#define P5LOAD(c, W0a, W0b, W1a, W1b, H0, H1)                                \
    do {                                                                     \
      const unsigned short* wo = wobase + (size_t)((c) * 8 + wave * 2) * 1024; \
      W0a = *(const short8*)(wo);        W0b = *(const short8*)(wo + 512);   \
      W1a = *(const short8*)(wo + 1024); W1b = *(const short8*)(wo + 1536);  \
      H0 = *(const f32x4*)(hby + (size_t)hr0 * 8192 + (c) * 512 + l32 * 16); \
      H1 = *(const f32x4*)(hby + (size_t)hr1 * 8192 + (c) * 512 + l32 * 16); \
    } while (0)
#define P5BODY(c, W0a, W0b, W1a, W1b, H0, H1)                                \
    do {                                                                     \
      char* rs = smem + ((c) & 1) * 4224;                                    \
      f32x4 a0 = (f32x4){0.f, 0.f, 0.f, 0.f};                                \
      a0 = MFMA16(W0a, bfrag[0], a0); a0 = MFMA16(W0b, bfrag[1], a0);        \
      f32x4 a1 = (f32x4){0.f, 0.f, 0.f, 0.f};                                \
      a1 = MFMA16(W1a, bfrag[0], a1); a1 = MFMA16(W1b, bfrag[1], a1);        \
      *(u16x4*)(rs + lo * 264 + (wave * 2) * 32 + hi * 8) = pack4(a0);       \
      *(u16x4*)(rs + lo * 264 + (wave * 2 + 1) * 32 + hi * 8) = pack4(a1);   \
      asm volatile("s_waitcnt lgkmcnt(0)" ::: "memory");                     \
      __builtin_amdgcn_s_barrier();                                          \
      u16x4 rv0 = *(const u16x4*)(rs + hr0 * 264 + l32 * 8);                 \
      u16x4 rv1 = *(const u16x4*)(rs + hr1 * 264 + l32 * 8);                 \
      f32x4 o0, o1;                                                          \
      _Pragma("unroll")                                                      \
      for (int r = 0; r < 4; ++r) {                                          \
        o0[r] = H0[r] + gate * bf2f(rv0[r]);                                 \
        o1[r] = H1[r] + gate * bf2f(rv1[r]);                                 \
      }                                                                      \
      __builtin_nontemporal_store(o0, (f32x4*)(ob + (size_t)hr0 * 8192 + (c) * 512 + l32 * 16)); \
      __builtin_nontemporal_store(o1, (f32x4*)(ob + (size_t)hr1 * 8192 + (c) * 512 + l32 * 16)); \
    } while (0)

    short8 wE0a, wE0b, wE1a, wE1b, wO0a, wO0b, wO1a, wO1b;
    f32x4 hE0, hE1, hO0, hO1;
    P5LOAD(0, wE0a, wE0b, wE1a, wE1b, hE0, hE1);
    #pragma unroll 1
    for (int p = 0; p < 8; ++p) {
      int c = 2 * p;
      P5LOAD(c + 1, wO0a, wO0b, wO1a, wO1b, hO0, hO1);
      P5BODY(c, wE0a, wE0b, wE1a, wE1b, hE0, hE1);
      if (p < 7) P5LOAD(c + 2, wE0a, wE0b, wE1a, wE1b, hE0, hE1);
      P5BODY(c + 1, wO0a, wO0b, wO1a, wO1b, hO0, hO1);
    }
#undef P5LOAD
#undef P5BODY
  }
}

extern "C" void kernel_launch(void* const* d_in, const int* in_sizes, int n_in,
                              void* d_out, int out_size, void* d_ws, size_t ws_size,
                              hipStream_t stream) {
  const float* hidden = (const float*)d_in[0];
  const float* bank   = (const float*)d_in[1];
  const float* Wq     = (const float*)d_in[2];
  const float* Wk     = (const float*)d_in[3];
  const float* Wv     = (const float*)d_in[4];
  const float* Wo     = (const float*)d_in[5];
  const float* gates  = (const float*)d_in[6];
  float* out = (float*)d_out;

  char* ws = (char*)d_ws;
  unsigned short* KF  = (unsigned short*)(ws);
  unsigned short* VF  = (unsigned short*)(ws + 262144);
  unsigned short* WqF = (unsigned short*)(ws + 524288);
  unsigned short* WoF = (unsigned short*)(ws + 2621440);

  pre_kv_kernel<<<1024, 64, 0, stream>>>(bank, Wk, Wv, KF, VF);
  pre_frag_kernel<<<1024, 256, 0, stream>>>(Wq, Wo, WqF, WoF);
  adapter_main<<<4096, 256, 0, stream>>>(hidden, KF, VF, WqF, WoF, gates, out);
}

// Round 11
// 389.487 us; speedup vs baseline: 1.0166x; 1.0166x over previous
//
#include <hip/hip_runtime.h>
#include <cstdint>
#include <cstddef>

// SummaryAdapter fused kernel for MI355X (gfx950), v11 = v8 (best, 315us) +
// three stall fixes:
//  (a) P1 write-one-ahead pipeline: LOAD(c+2) / WRITE(c+1) / MFMA(c) with two
//      static register sets - staging writes never wait on load latency.
//  (b) P5 raw s_barrier + lgkmcnt(0) only - out-stores are never drained by
//      barriers (no vmcnt(0) at __syncthreads).
//  (c) P5 h-loads prefetched one chunk ahead into named register sets.
// L=8 B=2 S=4096 D=2048 N=128 Ds=1024 Da=64.
//
// LDS map (24832 B, 6 blocks/CU):
//   stage 2 x [16][512B bf16 swizzled] @0..16384; after P1: qsc s66 @0,
//   Pb u16 s136 @4352, aob s66 @8704; scb f32 s132 @16384; resb u16 s520 @16384.
//
// Workspace layout (bytes):          off      size
//   KF  frag bf16                      0    262144
//   VF  frag bf16                 262144    262144
//   WqF frag bf16                 524288   2097152
//   WoF frag bf16                2621440   2097152
// Requires ws_size >= 4718592.

typedef __attribute__((ext_vector_type(8))) short short8;   // 8 x bf16
typedef __attribute__((ext_vector_type(4))) float f32x4;
typedef __attribute__((ext_vector_type(4))) unsigned short u16x4;

#define MFMA16(a, b, c) __builtin_amdgcn_mfma_f32_16x16x32_bf16((a), (b), (c), 0, 0, 0)

__device__ __forceinline__ unsigned short f2bf(float f) {
  unsigned int x = __builtin_bit_cast(unsigned int, f);
  x += 0x7fffu + ((x >> 16) & 1u);        // RNE
  return (unsigned short)(x >> 16);
}
__device__ __forceinline__ float bf2f(unsigned short u) {
  return __builtin_bit_cast(float, (unsigned int)u << 16);
}
__device__ __forceinline__ short8 cvt8v(f32x4 a, f32x4 b) {
  short8 r;
  r[0] = (short)f2bf(a[0]); r[1] = (short)f2bf(a[1]);
  r[2] = (short)f2bf(a[2]); r[3] = (short)f2bf(a[3]);
  r[4] = (short)f2bf(b[0]); r[5] = (short)f2bf(b[1]);
  r[6] = (short)f2bf(b[2]); r[7] = (short)f2bf(b[3]);
  return r;
}
__device__ __forceinline__ short8 ld_cvt8(const float* p) {
  f32x4 v0 = *(const f32x4*)p, v1 = *(const f32x4*)(p + 4);
  return cvt8v(v0, v1);
}
__device__ __forceinline__ u16x4 pack4(f32x4 v) {
  u16x4 r;
  r[0] = f2bf(v[0]); r[1] = f2bf(v[1]); r[2] = f2bf(v[2]); r[3] = f2bf(v[3]);
  return r;
}

// ---------------- pre 1: K = bank@Wk^T, V = bank@Wv^T via MFMA -------------
__global__ __launch_bounds__(64)
void pre_kv_kernel(const float* __restrict__ bank,
                   const float* __restrict__ Wk,
                   const float* __restrict__ Wv,
                   unsigned short* __restrict__ KF, unsigned short* __restrict__ VF) {
  int bid = blockIdx.x;
  int at = bid & 3, nt = (bid >> 2) & 7, kv = (bid >> 5) & 1;
  int b = (bid >> 6) & 1, l = bid >> 7;
  int lane = threadIdx.x & 63;
  int lo = lane & 15, hi = lane >> 4;
  const float* W  = (kv ? Wv : Wk) + (size_t)l * 65536;
  const float* bk = bank + (size_t)b * 131072;
  int lbq = l * 2 + b;
  f32x4 acc = (f32x4){0.f, 0.f, 0.f, 0.f};
  for (int ks = 0; ks < 32; ++ks) {
    short8 A = ld_cvt8(bk + (nt * 16 + lo) * 1024 + ks * 32 + hi * 8);
    short8 B = ld_cvt8(W + (at * 16 + lo) * 1024 + ks * 32 + hi * 8);
    acc = MFMA16(A, B, acc);
  }
  for (int r = 0; r < 4; ++r) {
    int n = nt * 16 + hi * 4 + r;
    int a = at * 16 + lo;
    unsigned short v = f2bf(acc[r]);
    if (kv == 0) {
      int idx = ((lbq * 8 + (n >> 4)) * 2 + (a >> 5)) * 512 +
                (((a >> 3) & 3) * 16 + (n & 15)) * 8 + (a & 7);
      KF[idx] = v;
    } else {
      int idx = ((lbq * 4 + (a >> 4)) * 4 + (n >> 5)) * 512 +
                (((n >> 3) & 3) * 16 + (a & 15)) * 8 + (n & 7);
      VF[idx] = v;
    }
  }
}

// ---------------- pre 2: Wq/Wo -> bf16 fragment layout ---------------------
__global__ void pre_frag_kernel(const float* __restrict__ Wq, const float* __restrict__ Wo,
                                unsigned short* __restrict__ WqF, unsigned short* __restrict__ WoF) {
  int idx = blockIdx.x * 256 + threadIdx.x;        // 262144 threads
  if (idx < 131072) {
    int t = idx;
    int lane = t & 63, ks = (t >> 6) & 63, at = (t >> 12) & 3, l = t >> 14;
    int a = at * 16 + (lane & 15), d = ks * 32 + (lane >> 4) * 8;
    *(short8*)(WqF + (size_t)t * 8) = ld_cvt8(Wq + ((size_t)(l * 64 + a)) * 2048 + d);
  } else {
    int t = idx - 131072;
    int lane = t & 63, ks = (t >> 6) & 1, dt = (t >> 7) & 127, l = t >> 14;
    int d = dt * 16 + (lane & 15), a = ks * 32 + (lane >> 4) * 8;
    *(short8*)(WoF + (size_t)t * 8) = ld_cvt8(Wo + ((size_t)(l * 2048 + d)) * 64 + a);
  }
}

// ---------------- main fused kernel ----------------------------------------
__global__ __launch_bounds__(256, 6)
void adapter_main(const float* __restrict__ hidden,
                  const unsigned short* __restrict__ KF, const unsigned short* __restrict__ VF,
                  const unsigned short* __restrict__ WqF, const unsigned short* __restrict__ WoF,
                  const float* __restrict__ gates, float* __restrict__ out) {
  __shared__ __align__(16) char smem[24832];
  float* qsc = (float*)smem;                        // [16] s66 f32
  unsigned short* Pb = (unsigned short*)(smem + 4352);  // [16] s136 u16
  float* aob = (float*)(smem + 8704);               // [16] s66 f32
  float* scb = (float*)(smem + 16384);              // [16] s132 f32
  char* resb = smem + 16384;                        // u16 [16][s520]

  // XCD-bijective swizzle (4096 % 8 == 0): XCD x gets 512 tiles = layer x.
  int bid0 = blockIdx.x;
  int bid = (bid0 & 7) * 512 + (bid0 >> 3);
  int st = bid & 255, b = (bid >> 8) & 1, l = bid >> 9;
  int tid = threadIdx.x, wave = tid >> 6, lane = tid & 63;
  int lo = lane & 15, hi = lane >> 4;
  size_t hbase = ((size_t)(l * 2 + b) * 4096 + st * 16) * 2048;
  const char* hby = (const char*)(hidden + hbase);
  float gate = 1.0f / (1.0f + __expf(-gates[l]));
  int lb = l * 2 + b;
  int at = wave;

  // ---- Phase 1: Q = h @ Wq^T; 8 chunks of 16 rows x 1KB; write-one-ahead ----
  f32x4 sregA[4], sregB[4];
  f32x4 qacc = (f32x4){0.f, 0.f, 0.f, 0.f};
  {
    const unsigned short* wqb = WqF + ((size_t)(l * 4 + at) * 64) * 512 + lane * 8;

#define LOADC(c, dst)                                                        \
    _Pragma("unroll")                                                        \
    for (int s2 = 0; s2 < 4; ++s2) {                                         \
      int row = s2 * 4 + wave;                                               \
      dst[s2] = *(const f32x4*)(hby + (size_t)row * 8192 + (size_t)(c) * 1024 + lane * 16); \
    }
#define WRITEC(c, src)                                                       \
    _Pragma("unroll")                                                        \
    for (int s2 = 0; s2 < 4; ++s2) {                                         \
      int row = s2 * 4 + wave;                                               \
      u16x4 pk = pack4(src[s2]);                                             \
      *(u16x4*)(smem + ((c) & 1) * 8192 + row * 512 + ((lane * 8) ^ ((row & 7) << 4))) = pk; \
    }

    LOADC(0, sregA); WRITEC(0, sregA); LOADC(1, sregB);
    #pragma unroll 1
    for (int c = 0; c < 8; ++c) {
      __syncthreads();                             // chunk c staged for all
      if ((c & 1) == 0) {
        if (c < 6) LOADC(c + 2, sregA);            // A free (written last iter)
        if (c < 7) WRITEC(c + 1, sregB);           // B loaded one iter ago
      } else {
        if (c < 6) LOADC(c + 2, sregB);
        if (c < 7) WRITEC(c + 1, sregA);
      }
      const char* rb = smem + (c & 1) * 8192 + lo * 512;
      int sw = (lo & 7) << 4;
      #pragma unroll
      for (int ks = 0; ks < 8; ++ks) {
        short8 A = *(const short8*)(rb + ((ks * 64 + hi * 16) ^ sw));
        short8 B = *(const short8*)(wqb + (size_t)(c * 8 + ks) * 512);
        qacc = MFMA16(A, B, qacc);
      }
    }
#undef LOADC
#undef WRITEC
  }
  __syncthreads();                                 // all chunk-7 reads done

  // ---- write Q (scaled) -> qsc @0 (stage dead) ----
  #pragma unroll
  for (int r = 0; r < 4; ++r)                      // fold 1/sqrt(64)
    qsc[(hi * 4 + r) * 66 + at * 16 + lo] = qacc[r] * 0.125f;
  __syncthreads();

  // ---- Phase 2: scores = Q @ K^T -> scb @16384 ----
  {
    short8 afrag[2];
    #pragma unroll
    for (int ks = 0; ks < 2; ++ks) {
      const float* qp = qsc + lo * 66 + ks * 32 + hi * 8;
      afrag[ks] = cvt8v(*(const f32x4*)qp, *(const f32x4*)(qp + 4));
    }
    #pragma unroll
    for (int i = 0; i < 2; ++i) {
      int nt = wave * 2 + i;
      f32x4 acc = (f32x4){0.f, 0.f, 0.f, 0.f};
      const unsigned short* kf = KF + ((size_t)(lb * 8 + nt) * 2) * 512 + lane * 8;
      acc = MFMA16(afrag[0], *(const short8*)(kf), acc);
      acc = MFMA16(afrag[1], *(const short8*)(kf + 512), acc);
      #pragma unroll
      for (int r = 0; r < 4; ++r)
        scb[(hi * 4 + r) * 132 + nt * 16 + lo] = acc[r];
    }
  }
  __syncthreads();

  // ---- Phase 3: softmax over N=128 (16 lanes per row) -> Pb bf16 ----
  {
    int row = wave * 4 + hi;
    const float* sp = scb + row * 132 + lo * 8;
    f32x4 v0 = *(const f32x4*)sp, v1 = *(const f32x4*)(sp + 4);
    float m = fmaxf(fmaxf(fmaxf(v0[0], v0[1]), fmaxf(v0[2], v0[3])),
                    fmaxf(fmaxf(v1[0], v1[1]), fmaxf(v1[2], v1[3])));
    m = fmaxf(m, __shfl_xor(m, 1)); m = fmaxf(m, __shfl_xor(m, 2));
    m = fmaxf(m, __shfl_xor(m, 4)); m = fmaxf(m, __shfl_xor(m, 8));
    f32x4 e0, e1; float s = 0.f;
    #pragma unroll
    for (int j = 0; j < 4; ++j) { e0[j] = __expf(v0[j] - m); s += e0[j]; }
    #pragma unroll
    for (int j = 0; j < 4; ++j) { e1[j] = __expf(v1[j] - m); s += e1[j]; }
    s += __shfl_xor(s, 1); s += __shfl_xor(s, 2);
    s += __shfl_xor(s, 4); s += __shfl_xor(s, 8);
    float inv = 1.0f / s;
    #pragma unroll
    for (int j = 0; j < 4; ++j) { e0[j] *= inv; e1[j] *= inv; }
    *(short8*)((char*)Pb + row * 272 + lo * 16) = cvt8v(e0, e1);
  }
  __syncthreads();

  // ---- Phase 4: attn_out = P @ V -> aob ----
  {
    short8 pfrag[4];
    #pragma unroll
    for (int ks = 0; ks < 4; ++ks)
      pfrag[ks] = *(const short8*)((const char*)Pb + lo * 272 + ks * 64 + hi * 16);
    const unsigned short* vf = VF + ((size_t)(lb * 4 + at) * 4) * 512 + lane * 8;
    f32x4 a = (f32x4){0.f, 0.f, 0.f, 0.f};
    #pragma unroll
    for (int ks = 0; ks < 4; ++ks)
      a = MFMA16(pfrag[ks], *(const short8*)(vf + (size_t)ks * 512), a);
    #pragma unroll
    for (int r = 0; r < 4; ++r)
      aob[(hi * 4 + r) * 68 + at * 16 + lo] = a[r];
  }
  __syncthreads();

  // ---- Phase 5: 8 d-chunks x 256 cols; raw barriers (lgkm only), h one
  //      chunk ahead in named register sets; stores never drained ----
  {
    short8 bfrag[2];
    #pragma unroll
    for (int ks = 0; ks < 2; ++ks) {
      const float* ap2 = aob + lo * 68 + ks * 32 + hi * 8;
      bfrag[ks] = cvt8v(*(const f32x4*)ap2, *(const f32x4*)(ap2 + 4));
    }
    char* ob = (char*)(out + hbase);
    f32x4 hA[4], hB[4];

#define HPREF(c, dst)                                                        \
    _Pragma("unroll")                                                        \
    for (int i2 = 0; i2 < 4; ++i2) {                                         \
      int row = i2 * 4 + wave;                                               \
      dst[i2] = *(const f32x4*)(hby + (size_t)row * 8192 + (size_t)(c) * 1024 + lane * 16); \
    }
#define P5CHUNK(c, hcur, hnext)                                              \
    do {                                                                     \
      _Pragma("unroll")                                                      \
      for (int j = 0; j < 4; ++j) {                                          \
        int dtl = wave * 4 + j;                                              \
        int dt = (c) * 16 + dtl;                                             \
        const unsigned short* wo = WoF + ((size_t)(l * 128 + dt) * 2) * 512 + lane * 8; \
        short8 A0 = *(const short8*)(wo);                                    \
        short8 A1 = *(const short8*)(wo + 512);                              \
        f32x4 acc = (f32x4){0.f, 0.f, 0.f, 0.f};                             \
        acc = MFMA16(A0, bfrag[0], acc);                                     \
        acc = MFMA16(A1, bfrag[1], acc);                                     \
        *(u16x4*)(resb + lo * 520 + dtl * 32 + hi * 8) = pack4(acc);         \
      }                                                                      \
      asm volatile("s_waitcnt lgkmcnt(0)" ::: "memory");                     \
      __builtin_amdgcn_s_barrier();                                          \
      __builtin_amdgcn_sched_barrier(0);                                     \
      if ((c) < 7) HPREF((c) + 1, hnext);                                    \
      _Pragma("unroll")                                                      \
      for (int i2 = 0; i2 < 4; ++i2) {                                       \
        int row = i2 * 4 + wave;                                             \
        size_t off = (size_t)row * 8192 + (size_t)(c) * 1024 + lane * 16;    \
        u16x4 rv = *(const u16x4*)(resb + row * 520 + lane * 8);             \
        f32x4 o;                                                             \
        _Pragma("unroll")                                                    \
        for (int r = 0; r < 4; ++r) o[r] = hcur[i2][r] + gate * bf2f(rv[r]); \
        __builtin_nontemporal_store(o, (f32x4*)(ob + off));                  \
      }                                                                      \
      asm volatile("s_waitcnt lgkmcnt(0)" ::: "memory");                     \
      __builtin_amdgcn_s_barrier();                                          \
      __builtin_amdgcn_sched_barrier(0);                                     \
    } while (0)

    HPREF(0, hA);
    #pragma unroll 1
    for (int p = 0; p < 4; ++p) {
      int c = 2 * p;
      P5CHUNK(c, hA, hB);
      P5CHUNK(c + 1, hB, hA);
    }
#undef HPREF
#undef P5CHUNK
  }
}

extern "C" void kernel_launch(void* const* d_in, const int* in_sizes, int n_in,
                              void* d_out, int out_size, void* d_ws, size_t ws_size,
                              hipStream_t stream) {
  const float* hidden = (const float*)d_in[0];
  const float* bank   = (const float*)d_in[1];
  const float* Wq     = (const float*)d_in[2];
  const float* Wk     = (const float*)d_in[3];
  const float* Wv     = (const float*)d_in[4];
  const float* Wo     = (const float*)d_in[5];
  const float* gates  = (const float*)d_in[6];
  float* out = (float*)d_out;

  char* ws = (char*)d_ws;
  unsigned short* KF  = (unsigned short*)(ws);
  unsigned short* VF  = (unsigned short*)(ws + 262144);
  unsigned short* WqF = (unsigned short*)(ws + 524288);
  unsigned short* WoF = (unsigned short*)(ws + 2621440);

  pre_kv_kernel<<<1024, 64, 0, stream>>>(bank, Wk, Wv, KF, VF);
  pre_frag_kernel<<<1024, 256, 0, stream>>>(Wq, Wo, WqF, WoF);
  adapter_main<<<4096, 256, 0, stream>>>(hidden, KF, VF, WqF, WoF, gates, out);
}

// Round 12
// 331.566 us; speedup vs baseline: 1.1942x; 1.1747x over previous
//
#include <hip/hip_runtime.h>
#include <cstdint>
#include <cstddef>

// SummaryAdapter fused kernel for MI355X (gfx950), v12 = R8 structure scaled
// to 32-row tiles (512 thr, 8 waves): halves weight-fragment load ratio
// (Wq 4:1 -> 2:1 per h-byte; Wo loads halved via per-wave mt-reuse) and
// halves barriers per byte. Lifetime-aliased LDS = 34048 B -> 4 blocks/CU
// at <=64 VGPR. All global h touches single-row coalesced (R8 pattern).
// L=8 B=2 S=4096 D=2048 N=128 Ds=1024 Da=64.
//
// LDS map (34048 B), lifetime-aliased:
//   P1 stage: 2 x [32 rows][256B bf16 swz] @0..16384
//   qsc f32 s66 @0        (end-P1 write; last chunk reads buf1 only)
//   Pb  u16 s136 @8448    (P3 write, P4 read)
//   scb f32 s132 @17152   (P2 write, P3 read)
//   aob f32 s66 @17152    (P4 write; scb dead)
//   resb u16 s260 @17152  (P5; aob read into regs + barrier first)
//
// Workspace layout (bytes):          off      size
//   KF  frag bf16                      0    262144
//   VF  frag bf16                 262144    262144
//   WqF frag bf16                 524288   2097152
//   WoF frag bf16                2621440   2097152
// Requires ws_size >= 4718592.

typedef __attribute__((ext_vector_type(8))) short short8;   // 8 x bf16
typedef __attribute__((ext_vector_type(4))) float f32x4;
typedef __attribute__((ext_vector_type(4))) unsigned short u16x4;

#define MFMA16(a, b, c) __builtin_amdgcn_mfma_f32_16x16x32_bf16((a), (b), (c), 0, 0, 0)

__device__ __forceinline__ unsigned short f2bf(float f) {
  unsigned int x = __builtin_bit_cast(unsigned int, f);
  x += 0x7fffu + ((x >> 16) & 1u);        // RNE
  return (unsigned short)(x >> 16);
}
__device__ __forceinline__ float bf2f(unsigned short u) {
  return __builtin_bit_cast(float, (unsigned int)u << 16);
}
__device__ __forceinline__ short8 cvt8v(f32x4 a, f32x4 b) {
  short8 r;
  r[0] = (short)f2bf(a[0]); r[1] = (short)f2bf(a[1]);
  r[2] = (short)f2bf(a[2]); r[3] = (short)f2bf(a[3]);
  r[4] = (short)f2bf(b[0]); r[5] = (short)f2bf(b[1]);
  r[6] = (short)f2bf(b[2]); r[7] = (short)f2bf(b[3]);
  return r;
}
__device__ __forceinline__ short8 ld_cvt8(const float* p) {
  f32x4 v0 = *(const f32x4*)p, v1 = *(const f32x4*)(p + 4);
  return cvt8v(v0, v1);
}
__device__ __forceinline__ u16x4 pack4(f32x4 v) {
  u16x4 r;
  r[0] = f2bf(v[0]); r[1] = f2bf(v[1]); r[2] = f2bf(v[2]); r[3] = f2bf(v[3]);
  return r;
}

// ---------------- pre 1: K = bank@Wk^T, V = bank@Wv^T via MFMA -------------
__global__ __launch_bounds__(64)
void pre_kv_kernel(const float* __restrict__ bank,
                   const float* __restrict__ Wk,
                   const float* __restrict__ Wv,
                   unsigned short* __restrict__ KF, unsigned short* __restrict__ VF) {
  int bid = blockIdx.x;
  int at = bid & 3, nt = (bid >> 2) & 7, kv = (bid >> 5) & 1;
  int b = (bid >> 6) & 1, l = bid >> 7;
  int lane = threadIdx.x & 63;
  int lo = lane & 15, hi = lane >> 4;
  const float* W  = (kv ? Wv : Wk) + (size_t)l * 65536;
  const float* bk = bank + (size_t)b * 131072;
  int lbq = l * 2 + b;
  f32x4 acc = (f32x4){0.f, 0.f, 0.f, 0.f};
  for (int ks = 0; ks < 32; ++ks) {
    short8 A = ld_cvt8(bk + (nt * 16 + lo) * 1024 + ks * 32 + hi * 8);
    short8 B = ld_cvt8(W + (at * 16 + lo) * 1024 + ks * 32 + hi * 8);
    acc = MFMA16(A, B, acc);
  }
  for (int r = 0; r < 4; ++r) {
    int n = nt * 16 + hi * 4 + r;
    int a = at * 16 + lo;
    unsigned short v = f2bf(acc[r]);
    if (kv == 0) {
      int idx = ((lbq * 8 + (n >> 4)) * 2 + (a >> 5)) * 512 +
                (((a >> 3) & 3) * 16 + (n & 15)) * 8 + (a & 7);
      KF[idx] = v;
    } else {
      int idx = ((lbq * 4 + (a >> 4)) * 4 + (n >> 5)) * 512 +
                (((n >> 3) & 3) * 16 + (a & 15)) * 8 + (n & 7);
      VF[idx] = v;
    }
  }
}

// ---------------- pre 2: Wq/Wo -> bf16 fragment layout ---------------------
__global__ void pre_frag_kernel(const float* __restrict__ Wq, const float* __restrict__ Wo,
                                unsigned short* __restrict__ WqF, unsigned short* __restrict__ WoF) {
  int idx = blockIdx.x * 256 + threadIdx.x;        // 262144 threads
  if (idx < 131072) {
    int t = idx;
    int lane = t & 63, ks = (t >> 6) & 63, at = (t >> 12) & 3, l = t >> 14;
    int a = at * 16 + (lane & 15), d = ks * 32 + (lane >> 4) * 8;
    *(short8*)(WqF + (size_t)t * 8) = ld_cvt8(Wq + ((size_t)(l * 64 + a)) * 2048 + d);
  } else {
    int t = idx - 131072;
    int lane = t & 63, ks = (t >> 6) & 1, dt = (t >> 7) & 127, l = t >> 14;
    int d = dt * 16 + (lane & 15), a = ks * 32 + (lane >> 4) * 8;
    *(short8*)(WoF + (size_t)t * 8) = ld_cvt8(Wo + ((size_t)(l * 2048 + d)) * 64 + a);
  }
}

// ---------------- main fused kernel ----------------------------------------
// 2048 blocks x 512 threads (8 waves), block owns one 32-row s-tile.
__global__ __launch_bounds__(512, 8)
void adapter_main(const float* __restrict__ hidden,
                  const unsigned short* __restrict__ KF, const unsigned short* __restrict__ VF,
                  const unsigned short* __restrict__ WqF, const unsigned short* __restrict__ WoF,
                  const float* __restrict__ gates, float* __restrict__ out) {
  __shared__ __align__(16) char smem[34048];
  float* qsc = (float*)smem;                           // [32] s66 f32
  unsigned short* Pb = (unsigned short*)(smem + 8448); // [32] s136 u16
  float* scb = (float*)(smem + 17152);                 // [32] s132 f32
  float* aob = (float*)(smem + 17152);                 // [32] s66 f32
  char* resb = smem + 17152;                           // u16 [32] s260

  // XCD-bijective swizzle (2048 % 8 == 0): XCD x gets 256 tiles = layer x, b=0/1.
  int bid0 = blockIdx.x;
  int bid = (bid0 & 7) * 256 + (bid0 >> 3);
  int st = bid & 127, b = (bid >> 7) & 1, l = bid >> 8;
  int tid = threadIdx.x, wave = tid >> 6, lane = tid & 63;
  int lo = lane & 15, hi = lane >> 4;
  int l32 = lane & 31, lh = lane >> 5;
  int mt = wave >> 2, at = wave & 3;
  size_t hbase = ((size_t)(l * 2 + b) * 4096 + st * 32) * 2048;
  const char* hby = (const char*)(hidden + hbase);
  float gate = 1.0f / (1.0f + __expf(-gates[l]));
  int lb = l * 2 + b;

  // ---- Phase 1: Q = h @ Wq^T; 16 chunks of 32 rows x 512B f32 ----
  // Load: s2 in {0,1}: row = (s2*8+wave)*2 + lh; 32 lanes x 16B per row.
  f32x4 sreg[2];
  f32x4 qacc = (f32x4){0.f, 0.f, 0.f, 0.f};
  {
    const unsigned short* wqb = WqF + ((size_t)(l * 4 + at) * 64) * 512 + lane * 8;
    int arow = mt * 16 + lo;
    int sw = (arow & 7) << 4;

#define LOADC(c)                                                             \
    _Pragma("unroll")                                                        \
    for (int s2 = 0; s2 < 2; ++s2) {                                         \
      int row = (s2 * 8 + wave) * 2 + lh;                                    \
      sreg[s2] = *(const f32x4*)(hby + (size_t)row * 8192 + (size_t)(c) * 512 + l32 * 16); \
    }
#define WRITEC(c)                                                            \
    _Pragma("unroll")                                                        \
    for (int s2 = 0; s2 < 2; ++s2) {                                         \
      int row = (s2 * 8 + wave) * 2 + lh;                                    \
      u16x4 pk = pack4(sreg[s2]);                                            \
      *(u16x4*)(smem + ((c) & 1) * 8192 + row * 256 + ((l32 * 8) ^ ((row & 7) << 4))) = pk; \
    }

    LOADC(0); WRITEC(0);
    #pragma unroll 1
    for (int c = 0; c < 16; ++c) {
      __syncthreads();                             // chunk c staged for all
      if (c < 15) LOADC(c + 1);
      const char* rb = smem + (c & 1) * 8192 + arow * 256;
      #pragma unroll
      for (int ks = 0; ks < 4; ++ks) {
        short8 A = *(const short8*)(rb + ((ks * 64 + hi * 16) ^ sw));
        short8 B = *(const short8*)(wqb + (size_t)(c * 4 + ks) * 512);
        qacc = MFMA16(A, B, qacc);
      }
      if (c < 15) WRITEC(c + 1);
    }
#undef LOADC
#undef WRITEC
  }
  __syncthreads();                                 // all chunk-15 reads done

  // ---- write Q (scaled) -> qsc @0 (stage buf0 dead since iter-15 sync) ----
  #pragma unroll
  for (int r = 0; r < 4; ++r)                      // fold 1/sqrt(64)
    qsc[(mt * 16 + hi * 4 + r) * 66 + at * 16 + lo] = qacc[r] * 0.125f;
  __syncthreads();

  // ---- Phase 2: scores = Q @ K^T -> scb (wave -> mt x ntpair) ----
  {
    short8 afrag[2];
    #pragma unroll
    for (int ks = 0; ks < 2; ++ks) {
      const float* qp = qsc + (mt * 16 + lo) * 66 + ks * 32 + hi * 8;
      afrag[ks] = cvt8v(*(const f32x4*)qp, *(const f32x4*)(qp + 4));
    }
    #pragma unroll
    for (int i = 0; i < 2; ++i) {
      int nt = at * 2 + i;                         // 0..7
      f32x4 acc = (f32x4){0.f, 0.f, 0.f, 0.f};
      const unsigned short* kf = KF + ((size_t)(lb * 8 + nt) * 2) * 512 + lane * 8;
      acc = MFMA16(afrag[0], *(const short8*)(kf), acc);
      acc = MFMA16(afrag[1], *(const short8*)(kf + 512), acc);
      #pragma unroll
      for (int r = 0; r < 4; ++r)
        scb[(mt * 16 + hi * 4 + r) * 132 + nt * 16 + lo] = acc[r];
    }
  }
  __syncthreads();

  // ---- Phase 3: softmax over N=128 (16 lanes per row) -> Pb bf16 ----
  {
    int row = wave * 4 + hi;                       // 0..31
    const float* sp = scb + row * 132 + lo * 8;
    f32x4 v0 = *(const f32x4*)sp, v1 = *(const f32x4*)(sp + 4);
    float m = fmaxf(fmaxf(fmaxf(v0[0], v0[1]), fmaxf(v0[2], v0[3])),
                    fmaxf(fmaxf(v1[0], v1[1]), fmaxf(v1[2], v1[3])));
    m = fmaxf(m, __shfl_xor(m, 1)); m = fmaxf(m, __shfl_xor(m, 2));
    m = fmaxf(m, __shfl_xor(m, 4)); m = fmaxf(m, __shfl_xor(m, 8));
    f32x4 e0, e1; float s = 0.f;
    #pragma unroll
    for (int j = 0; j < 4; ++j) { e0[j] = __expf(v0[j] - m); s += e0[j]; }
    #pragma unroll
    for (int j = 0; j < 4; ++j) { e1[j] = __expf(v1[j] - m); s += e1[j]; }
    s += __shfl_xor(s, 1); s += __shfl_xor(s, 2);
    s += __shfl_xor(s, 4); s += __shfl_xor(s, 8);
    float inv = 1.0f / s;
    #pragma unroll
    for (int j = 0; j < 4; ++j) { e0[j] *= inv; e1[j] *= inv; }
    *(short8*)((char*)Pb + row * 272 + lo * 16) = cvt8v(e0, e1);
  }
  __syncthreads();

  // ---- Phase 4: attn_out = P @ V -> aob (scb dead) ----
  {
    short8 pfrag[4];
    #pragma unroll
    for (int ks = 0; ks < 4; ++ks)
      pfrag[ks] = *(const short8*)((const char*)Pb + (mt * 16 + lo) * 272 + ks * 64 + hi * 16);
    const unsigned short* vf = VF + ((size_t)(lb * 4 + at) * 4) * 512 + lane * 8;
    f32x4 a = (f32x4){0.f, 0.f, 0.f, 0.f};
    #pragma unroll
    for (int ks = 0; ks < 4; ++ks)
      a = MFMA16(pfrag[ks], *(const short8*)(vf + (size_t)ks * 512), a);
    #pragma unroll
    for (int r = 0; r < 4; ++r)
      aob[(mt * 16 + hi * 4 + r) * 66 + at * 16 + lo] = a[r];
  }
  __syncthreads();

  // ---- Phase 5: 8 d-chunks of 256 cols; MFMA->resb->coalesced add ----
  {
    short8 bfrag[2][2];                            // [mt2][ks]
    #pragma unroll
    for (int m2 = 0; m2 < 2; ++m2)
      #pragma unroll
      for (int ks = 0; ks < 2; ++ks) {
        const float* ap2 = aob + (m2 * 16 + lo) * 66 + ks * 32 + hi * 8;
        bfrag[m2][ks] = cvt8v(*(const f32x4*)ap2, *(const f32x4*)(ap2 + 4));
      }
    __syncthreads();                               // aob fully read; resb free
    char* ob = (char*)(out + hbase);
    #pragma unroll 1
    for (int c = 0; c < 8; ++c) {
      #pragma unroll
      for (int j = 0; j < 2; ++j) {
        int dtl = wave * 2 + j;                    // 0..15 within chunk
        int dt = c * 16 + dtl;
        const unsigned short* wo = WoF + ((size_t)(l * 128 + dt) * 2) * 512 + lane * 8;
        short8 A0 = *(const short8*)(wo);
        short8 A1 = *(const short8*)(wo + 512);
        #pragma unroll
        for (int m2 = 0; m2 < 2; ++m2) {           // reuse A0/A1 for both halves
          f32x4 acc = (f32x4){0.f, 0.f, 0.f, 0.f};
          acc = MFMA16(A0, bfrag[m2][0], acc);
          acc = MFMA16(A1, bfrag[m2][1], acc);
          *(u16x4*)(resb + (m2 * 16 + lo) * 520 + dtl * 32 + hi * 8) = pack4(acc);
        }
      }
      __syncthreads();                             // resid chunk c ready
      #pragma unroll
      for (int i2 = 0; i2 < 4; ++i2) {
        int row = i2 * 8 + wave;                   // 0..31, 1 row per instr
        size_t off = (size_t)row * 8192 + (size_t)c * 1024 + lane * 16;
        f32x4 hv = *(const f32x4*)(hby + off);     // L2/L3 hit (read in P1)
        u16x4 rv = *(const u16x4*)(resb + row * 520 + lane * 8);
        f32x4 o;
        #pragma unroll
        for (int r = 0; r < 4; ++r) o[r] = hv[r] + gate * bf2f(rv[r]);
        __builtin_nontemporal_store(o, (f32x4*)(ob + off));
      }
      __syncthreads();                             // resb reads done
    }
  }
}

extern "C" void kernel_launch(void* const* d_in, const int* in_sizes, int n_in,
                              void* d_out, int out_size, void* d_ws, size_t ws_size,
                              hipStream_t stream) {
  const float* hidden = (const float*)d_in[0];
  const float* bank   = (const float*)d_in[1];
  const float* Wq     = (const float*)d_in[2];
  const float* Wk     = (const float*)d_in[3];
  const float* Wv     = (const float*)d_in[4];
  const float* Wo     = (const float*)d_in[5];
  const float* gates  = (const float*)d_in[6];
  float* out = (float*)d_out;

  char* ws = (char*)d_ws;
  unsigned short* KF  = (unsigned short*)(ws);
  unsigned short* VF  = (unsigned short*)(ws + 262144);
  unsigned short* WqF = (unsigned short*)(ws + 524288);
  unsigned short* WoF = (unsigned short*)(ws + 2621440);

  pre_kv_kernel<<<1024, 64, 0, stream>>>(bank, Wk, Wv, KF, VF);
  pre_frag_kernel<<<1024, 256, 0, stream>>>(Wq, Wo, WqF, WoF);
  adapter_main<<<2048, 512, 0, stream>>>(hidden, KF, VF, WqF, WoF, gates, out);
}